// Round 2
// baseline (6571.136 us; speedup 1.0000x reference)
//
#include <hip/hip_runtime.h>
#include <hip/hip_bf16.h>

// Problem constants
#define B_WIN 4096
#define NTOK 49
#define CDIM 384
#define NHEAD 12
#define HD 32
#define HALF 192
#define NW 64
#define TBL 169
#define HID 512
#define NM (NTOK * NTOK)          // 2401
#define TOKC (NTOK * CDIM)        // 18816
#define QKVS (NTOK * HD)          // 1568 floats per slice

// ---------------------------------------------------------------------------
// Kernel 1: CPB MLP -> table16[t][h] = 16*sigmoid( relu(coords@w1.T+b1) @ w2.T )
// ---------------------------------------------------------------------------
__global__ __launch_bounds__(256) void cpb_kernel(
    const float* __restrict__ coords, const float* __restrict__ w1,
    const float* __restrict__ b1, const float* __restrict__ w2,
    float* __restrict__ table16)
{
    __shared__ float hid[HID];
    const int t = blockIdx.x;                 // 0..168
    const int tid = threadIdx.x;
    const float c0 = coords[t * 2 + 0];
    const float c1 = coords[t * 2 + 1];
    for (int j = tid; j < HID; j += 256) {
        float h = fmaf(c0, w1[j * 2 + 0], fmaf(c1, w1[j * 2 + 1], b1[j]));
        hid[j] = fmaxf(h, 0.f);
    }
    __syncthreads();
    if (tid < 192) {
        const int h = tid >> 4;               // 0..11
        const int l = tid & 15;
        float s = 0.f;
        for (int j = l; j < HID; j += 16) s += hid[j] * w2[h * HID + j];
        s += __shfl_xor(s, 8);
        s += __shfl_xor(s, 4);
        s += __shfl_xor(s, 2);
        s += __shfl_xor(s, 1);
        if (l == 0) table16[t * NHEAD + h] = 16.f / (1.f + expf(-s));
    }
}

// ---------------------------------------------------------------------------
// Kernel 2: fused QKV half-slice GEMM + ghost + cosine attention per (b, hh)
//   grid = 4096*6, block = 192 (3 waves)
//   Phase 1 stages BOTH x and the 96 W rows in LDS (K-chunks of 48) so all
//   global reads are coalesced; inner loop reads W per-lane from LDS
//   (pad 52 -> max 8-way bank alias, amortized 25x) and x as broadcast.
//   LDS: qkv 18.8KB + buf 29.6KB + gsl -> ~49KB -> 3 blocks/CU (9 waves).
// ---------------------------------------------------------------------------
#define KC 48                     // K-chunk
#define NKC 8                     // 384 / 48
#define WLP 52                    // padded row stride (floats) of W tile
#define WLOFF 2400                // float offset of W tile inside buf (xs = 50*48)

__global__ __launch_bounds__(192, 2) void attn_kernel(
    const float* __restrict__ x, const float* __restrict__ mask,
    const float* __restrict__ Wq, const float* __restrict__ Wk,
    const float* __restrict__ Wv, const float* __restrict__ gq,
    const float* __restrict__ gk, const float* __restrict__ gv,
    const float* __restrict__ ls, const int* __restrict__ rpi,
    const float* __restrict__ table16, float* __restrict__ out)
{
    __shared__ __align__(16) float qkv[3 * QKVS];   // q [49][32], kT [32][49], v [49][32]
    // phase1: xs [50][48] (2400 fl) + Wl [96][52] (4992 fl) = 7392 fl
    // phase2: logits 2*2401 + norms 196 at 4802+  (all < 7392)
    __shared__ __align__(16) float buf[7392];
    __shared__ float gsl[96];                       // g slices for q,k,v

    const int bidx = blockIdx.x;
    const int b = bidx / 6;
    const int hh = bidx % 6;
    const int tid = threadIdx.x;

    if (tid < 96) {
        const int mm = tid >> 5, d = tid & 31;
        const float* g = (mm == 0) ? gq : ((mm == 1) ? gk : gv);
        gsl[tid] = g[32 * hh + d];
    }

    // ---------------- Phase 1: q/k/v half-slice GEMM ----------------
    const float4* xb4 = (const float4*)(x + (size_t)b * TOKC);
    float4* xs4 = (float4*)buf;                     // [50][12] float4
    float4* Wl4 = (float4*)(buf + WLOFF);           // row stride 13 float4

    const int c = tid % 96;                  // output column (q:0-31, k:32-63, v:64-95)
    const int half = tid / 96;               // row half
    const int n0 = half * 25;                // rows n0..n0+24 (row 49 is zero dummy)
    const int m = c >> 5;
    const int j = c & 31;

    float acc[25];
#pragma unroll
    for (int r = 0; r < 25; ++r) acc[r] = 0.f;

    for (int kc = 0; kc < NKC; ++kc) {
        __syncthreads();
        // stage x[:, kc*48 .. +48) into xs[50][48]
        for (int i = tid; i < 600; i += 192) {
            const int n = i / 12, c4 = i % 12;
            xs4[n * 12 + c4] = (n < NTOK) ? xb4[n * 96 + kc * 12 + c4]
                                          : make_float4(0.f, 0.f, 0.f, 0.f);
        }
        // stage 96 W rows x 48 k into Wl[96][52] (coalesced: 12 lanes per row)
        for (int i = tid; i < 1152; i += 192) {
            const int cc = i / 12, kk = i % 12;
            const float* wm = (cc < 32) ? Wq : ((cc < 64) ? Wk : Wv);
            const float4* wr4 = (const float4*)(wm + (size_t)(32 * hh + (cc & 31)) * CDIM);
            Wl4[cc * 13 + kk] = wr4[kc * 12 + kk];
        }
        __syncthreads();
#pragma unroll 2
        for (int kk = 0; kk < 12; ++kk) {
            const float4 w4 = Wl4[c * 13 + kk];
#pragma unroll
            for (int r = 0; r < 25; ++r) {
                const float4 x4 = xs4[(n0 + r) * 12 + kk];   // wave-uniform broadcast
                acc[r] = fmaf(x4.x, w4.x,
                         fmaf(x4.y, w4.y,
                         fmaf(x4.z, w4.z,
                         fmaf(x4.w, w4.w, acc[r]))));
            }
        }
    }
    __syncthreads();
    // store slices: q row-major, k transposed (kills stride-32 bank conflict), v row-major
#pragma unroll
    for (int r = 0; r < 25; ++r) {
        const int n = n0 + r;
        if (n < NTOK) {
            if (m == 1)      qkv[QKVS + j * NTOK + n] = acc[r];
            else if (m == 0) qkv[n * HD + j]          = acc[r];
            else             qkv[2 * QKVS + n * HD + j] = acc[r];
        }
    }
    __syncthreads();

    // ---------------- Phase 2a: inverse norms (var A = plain, var B = ghost) ----
    for (int task = tid; task < 196; task += 192) {
        const int n = task % 49;
        const int qk = (task / 49) & 1;          // 0 = q, 1 = k
        const int var = task / 98;               // 0 = head hh, 1 = head hh+6
        float s = 0.f;
#pragma unroll
        for (int d = 0; d < 32; ++d) {
            float v = (qk == 0) ? qkv[n * HD + d] : qkv[QKVS + d * NTOK + n];
            if (var) v *= gsl[qk * 32 + d];
            s += v * v;
        }
        buf[4802 + task] = 1.f / sqrtf(s);
    }
    __syncthreads();

    // ---------------- Phase 2b: logits + scale + rpb + mask ----------------
    const float* maskw = mask + (size_t)(b & 63) * NM;
    const float lsA = expf(fminf(ls[hh], 4.6051702f));
    const float lsB = expf(fminf(ls[hh + 6], 4.6051702f));
    for (int e = tid; e < 2 * NM; e += 192) {
        const int var = (e >= NM) ? 1 : 0;
        const int nm = var ? (e - NM) : e;
        const int n = nm / 49, mm = nm % 49;
        float s = 0.f;
        if (!var) {
#pragma unroll
            for (int d = 0; d < 32; ++d)
                s = fmaf(qkv[n * HD + d], qkv[QKVS + d * NTOK + mm], s);
        } else {
#pragma unroll
            for (int d = 0; d < 32; ++d)
                s = fmaf(qkv[n * HD + d] * (gsl[d] * gsl[32 + d]),
                         qkv[QKVS + d * NTOK + mm], s);
        }
        const float invq = buf[4802 + var * 98 + n];
        const float invk = buf[4802 + var * 98 + 49 + mm];
        const float scale = var ? lsB : lsA;
        const int h = var ? (hh + 6) : hh;
        const float rp = table16[rpi[nm] * NHEAD + h];
        buf[e] = s * invq * invk * scale + rp + maskw[nm];
    }
    __syncthreads();

    // ---------------- Phase 2c: row softmax ----------------
    if (tid < 98) {
        const int var = tid / 49, n = tid % 49;
        float* row = buf + var * NM + n * 49;
        float mx = row[0];
        for (int i2 = 1; i2 < 49; ++i2) mx = fmaxf(mx, row[i2]);
        float sum = 0.f;
        for (int i2 = 0; i2 < 49; ++i2) { float p = expf(row[i2] - mx); row[i2] = p; sum += p; }
        const float inv = 1.f / sum;
        for (int i2 = 0; i2 < 49; ++i2) row[i2] *= inv;
    }
    __syncthreads();

    // ---------------- Phase 2d: PV + write ----------------
    float* outb = out + (size_t)b * TOKC;
    for (int task = tid; task < 2 * QKVS; task += 192) {
        const int var = task / QKVS;
        const int rest = task - var * QKVS;
        const int n = rest / HD, d = rest & 31;
        const float* p = buf + var * NM + n * 49;
        float s = 0.f;
#pragma unroll
        for (int mm2 = 0; mm2 < 49; ++mm2)
            s = fmaf(p[mm2], qkv[2 * QKVS + mm2 * HD + d], s);
        if (var) s *= gsl[64 + d];
        outb[n * CDIM + (var ? (hh + 6) : hh) * HD + d] = s;
    }
}

// ---------------------------------------------------------------------------
// Kernel 3: per-window in-place projection GEMM on d_out
//   grid = 4096, block = 384 (6 waves); thread = one output column
//   (VALU-bound per cycle model: 113k VALU-cy vs 74k TA-cy per CU -> leave
//    the per-thread W-row walk; W is L2-resident.)
// ---------------------------------------------------------------------------
__global__ __launch_bounds__(384, 3) void proj_kernel(
    const float* __restrict__ pw, const float* __restrict__ pb,
    float* __restrict__ out)
{
    __shared__ __align__(16) float A[TOKC];   // 49*384 floats
    const int b = blockIdx.x;
    const int tid = threadIdx.x;
    float4* A4 = (float4*)A;
    const float4* o4 = (const float4*)(out + (size_t)b * TOKC);
    for (int i = tid; i < TOKC / 4; i += 384) A4[i] = o4[i];
    __syncthreads();

    const int j = tid;                        // 0..383
    float acc[49];
    const float bias = pb[j];
#pragma unroll
    for (int n = 0; n < 49; ++n) acc[n] = bias;

    const float4* w4p = (const float4*)(pw + (size_t)j * CDIM);
#pragma unroll 2
    for (int kk = 0; kk < 96; ++kk) {
        const float4 w4 = w4p[kk];
#pragma unroll
        for (int n = 0; n < 49; ++n) {
            const float4 x4 = A4[n * 96 + kk];   // wave-uniform broadcast
            acc[n] = fmaf(x4.x, w4.x,
                     fmaf(x4.y, w4.y,
                     fmaf(x4.z, w4.z,
                     fmaf(x4.w, w4.w, acc[n]))));
        }
    }
    float* ob = out + (size_t)b * TOKC;
    for (int n = 0; n < 49; ++n) ob[n * CDIM + j] = acc[n];
}

// ---------------------------------------------------------------------------
extern "C" void kernel_launch(void* const* d_in, const int* in_sizes, int n_in,
                              void* d_out, int out_size, void* d_ws, size_t ws_size,
                              hipStream_t stream)
{
    const float* x      = (const float*)d_in[0];
    const float* mask   = (const float*)d_in[1];
    const float* Wq     = (const float*)d_in[2];
    const float* Wk     = (const float*)d_in[3];
    const float* Wv     = (const float*)d_in[4];
    const float* gq     = (const float*)d_in[5];
    const float* gk     = (const float*)d_in[6];
    const float* gv     = (const float*)d_in[7];
    const float* ls     = (const float*)d_in[8];
    const float* coords = (const float*)d_in[9];
    const float* w1     = (const float*)d_in[10];
    const float* b1     = (const float*)d_in[11];
    const float* w2     = (const float*)d_in[12];
    const float* pw     = (const float*)d_in[13];
    const float* pb     = (const float*)d_in[14];
    const int*   rpi    = (const int*)d_in[15];
    float* out = (float*)d_out;
    float* table16 = (float*)d_ws;            // 169*12 floats = 8112 B

    cpb_kernel<<<TBL, 256, 0, stream>>>(coords, w1, b1, w2, table16);
    attn_kernel<<<B_WIN * 6, 192, 0, stream>>>(x, mask, Wq, Wk, Wv, gq, gk, gv,
                                               ls, rpi, table16, out);
    proj_kernel<<<B_WIN, 384, 0, stream>>>(pw, pb, out);
}